// Round 5
// baseline (264.308 us; speedup 1.0000x reference)
//
#include <hip/hip_runtime.h>
#include <math.h>

// Problem dims (fixed by the reference)
#define B_ 8
#define L_ 8192
#define H_ 128
#define N_ 32
#define C_ 128   // chunks along L (= threads per k_s4d block)
#define T_ 64    // chunk length (C_*T_ == L_)

// ws layout:
//   Whi ushort[256*128] @ 0        (64 KB)  bf16 hi part of out_w, [g][h]
//   Wlo ushort[256*128] @ 65536    (64 KB)  bf16 lo part (w - hi)
//   gyb ushort[B_*H_*L_] @ 131072  (16 MB)  bf16 gy, layout [b][T(128)][h(128)][v(64)]
// l' = T*64+v = t*128+c (fixed permutation of l; mix+pool is order-invariant)

typedef __attribute__((ext_vector_type(8))) short short8;
typedef __attribute__((ext_vector_type(4))) float f32x4;

__device__ __forceinline__ unsigned short f2bf(float f) {
    unsigned int u = __float_as_uint(f);
    return (unsigned short)((u + 0x7FFFu + ((u >> 16) & 1u)) >> 16);
}
__device__ __forceinline__ float bf2f(unsigned short h) {
    return __uint_as_float(((unsigned int)h) << 16);
}

__device__ __forceinline__ float gelu_tanh(float y) {
    float t = 0.7978845608028654f * fmaf(0.044715f, y * y * y, y);
    float e = __expf(2.f * t);
    float th = 1.f - __fdividef(2.f, e + 1.f);
    return 0.5f * y * (1.f + th);
}

// ---------------------------------------------------------------------------
// k_setup: split out_w into bf16 hi/lo (native [g][h] layout = MFMA A operand)
// + out init
// ---------------------------------------------------------------------------
__global__ __launch_bounds__(256) void k_setup(
    const float* __restrict__ out_w, const float* __restrict__ dec_b,
    float* __restrict__ out, unsigned short* __restrict__ Whi,
    unsigned short* __restrict__ Wlo)
{
    int blk = blockIdx.x, tid = threadIdx.x;
    if (blk < 128) {
        int idx = blk * 256 + tid;            // 0..32767 = g*128+h
        float w = out_w[idx];
        unsigned short hi = f2bf(w);
        Whi[idx] = hi;
        Wlo[idx] = f2bf(w - bf2f(hi));
    } else {
        if (tid < B_) out[tid] = dec_b[0];
    }
}

// ---------------------------------------------------------------------------
// k_s4d: fused encoder + chunked S4D scan + skip + GELU -> bf16 gy.
// Block=(b,h), 128 threads (2 waves), thread = chunk c.
// Plain 256-VGPR cap (R3: tighter bound -> 3.7 GB spill, 7x regression).
// ---------------------------------------------------------------------------
__global__ __launch_bounds__(128, 2) void k_s4d(
    const float* __restrict__ x, const float* __restrict__ enc_w,
    const float* __restrict__ enc_b, const float* __restrict__ log_dt,
    const float* __restrict__ log_A_real, const float* __restrict__ A_imag,
    const float* __restrict__ C_re, const float* __restrict__ C_im,
    const float* __restrict__ Dp, unsigned short* __restrict__ gyb)
{
    const int bh = blockIdx.x;
    const int b = bh >> 7, h = bh & (H_ - 1);
    const int c = threadIdx.x;
    const int lane = c & 63, wv = c >> 6;

    __shared__ float4 cw4[N_];        // (wr, wi, coef_r, coef_i)
    __shared__ float4 pw[N_];         // (w2r, w2i, wr, wi)
    __shared__ float2 wTpow[7][N_];   // wT^(2^k)
    __shared__ float2 Sx[N_][64];     // wave-0 inclusive scans (16 KB)

    if (c < N_) {
        int idx = h * N_ + c;
        float dt = expf(log_dt[h]);
        float Ar = -expf(log_A_real[idx]);
        float Ai = A_imag[idx];
        float ar = dt * Ar, ai = dt * Ai;
        float er = expf(ar);
        float wr = er * cosf(ai), wi = er * sinf(ai);
        float numr = wr - 1.f, numi = wi;
        float inv = 1.f / (Ar * Ar + Ai * Ai);
        float qr = (numr * Ar + numi * Ai) * inv;
        float qi = (numi * Ar - numr * Ai) * inv;
        cw4[c] = make_float4(wr, wi, C_re[idx] * qr - C_im[idx] * qi,
                                     C_re[idx] * qi + C_im[idx] * qr);
        pw[c] = make_float4(wr * wr - wi * wi, 2.f * wr * wi, wr, wi);
        float erT = expf(ar * (float)T_);
        float pr = erT * cosf(ai * (float)T_), pi = erT * sinf(ai * (float)T_);
#pragma unroll
        for (int k = 0; k < 7; ++k) {
            wTpow[k][c] = make_float2(pr, pi);
            float nr = pr * pr - pi * pi;
            pi = 2.f * pr * pi; pr = nr;
        }
    }
    __syncthreads();

    const float2* xb = (const float2*)x + (size_t)b * L_ + c * T_;
    const float ew0 = enc_w[h], ew1 = enc_w[H_ + h], eb = enc_b[h];

    // ---- Phase 1: E[c] via w^2 double-steps, n tiled by 4 ----
    float zr[N_], zi[N_];
#pragma unroll
    for (int n = 0; n < N_; ++n) { zr[n] = 0.f; zi[n] = 0.f; }

#pragma unroll 1
    for (int tt = 0; tt < T_ / 16; ++tt) {
        float u[16];
        const float4* xq = (const float4*)xb + tt * 8;
#pragma unroll
        for (int j = 0; j < 8; ++j) {
            float4 xv = xq[j];
            u[2 * j]     = fmaf(xv.x, ew0, fmaf(xv.y, ew1, eb));
            u[2 * j + 1] = fmaf(xv.z, ew0, fmaf(xv.w, ew1, eb));
        }
#pragma unroll
        for (int ng = 0; ng < 8; ++ng) {
            float4 q[4];
#pragma unroll
            for (int m = 0; m < 4; ++m) q[m] = pw[ng * 4 + m];
#pragma unroll
            for (int m = 0; m < 4; ++m) {
                int n = ng * 4 + m;
                float ar_ = zr[n], ai_ = zi[n];
#pragma unroll
                for (int t2 = 0; t2 < 8; ++t2) {
                    float ua = u[2 * t2], ub = u[2 * t2 + 1];
                    float mr = fmaf(q[m].z, ua, ub);
                    float mi = q[m].w * ua;
                    float nr = fmaf(q[m].x, ar_, fmaf(-q[m].y, ai_, mr));
                    ai_ = fmaf(q[m].x, ai_, fmaf(q[m].y, ar_, mi));
                    ar_ = nr;
                }
                zr[n] = ar_; zi[n] = ai_;
            }
        }
    }

    // ---- Phase 2: scan over chunks ----
#pragma unroll
    for (int k = 0; k < 6; ++k) {
        int s = 1 << k;
        float mask = (lane >= s) ? 1.f : 0.f;
#pragma unroll
        for (int n = 0; n < N_; ++n) {
            float2 q = wTpow[k][n];
            float vr = __shfl_up(zr[n], s, 64);
            float vi = __shfl_up(zi[n], s, 64);
            float adr = fmaf(q.x, vr, -(q.y * vi));
            float adi = fmaf(q.x, vi, q.y * vr);
            zr[n] = fmaf(mask, adr, zr[n]);
            zi[n] = fmaf(mask, adi, zi[n]);
        }
    }
    if (wv == 0) {
#pragma unroll
        for (int n = 0; n < N_; ++n) Sx[n][lane] = make_float2(zr[n], zi[n]);
    }
    __syncthreads();
    if (wv == 1) {
#pragma unroll
        for (int n = 0; n < N_; ++n) {
            float2 q = wTpow[6][n];
            float2 v = Sx[n][lane];
            zr[n] = fmaf(q.x, v.x, fmaf(-q.y, v.y, zr[n]));
            zi[n] = fmaf(q.x, v.y, fmaf(q.y, v.x, zi[n]));
        }
    }
    {
        bool l0 = (lane == 0);
#pragma unroll
        for (int n = 0; n < N_; ++n) {
            float2 bv = Sx[n][63];
            float br = (wv == 1) ? bv.x : 0.f;
            float bi = (wv == 1) ? bv.y : 0.f;
            float tr = __shfl_up(zr[n], 1, 64);
            float ti = __shfl_up(zi[n], 1, 64);
            zr[n] = l0 ? br : tr;
            zi[n] = l0 ? bi : ti;
        }
    }

    // ---- Phase 3: replay with incoming state; skip+GELU; bf16 store ----
    // store layout: gyb[((b*128 + (t*2+wv))*128 + h)*64 + lane], t=t4*4+j
    const float Dh = Dp[h];
    unsigned short* gb = gyb + (size_t)b * (128 * 128 * 64)
                             + (size_t)wv * 8192 + h * 64 + lane;
    const float4* xq = (const float4*)xb;
    float4 xa = xq[0], xbv = xq[1];
#pragma unroll 1
    for (int t4 = 0; t4 < T_ / 4; ++t4) {
        float4 na, nb;
        if (t4 < T_ / 4 - 1) { na = xq[2 * t4 + 2]; nb = xq[2 * t4 + 3]; }
        float u[4], p[4];
        u[0] = fmaf(xa.x, ew0, fmaf(xa.y, ew1, eb));
        u[1] = fmaf(xa.z, ew0, fmaf(xa.w, ew1, eb));
        u[2] = fmaf(xbv.x, ew0, fmaf(xbv.y, ew1, eb));
        u[3] = fmaf(xbv.z, ew0, fmaf(xbv.w, ew1, eb));
#pragma unroll
        for (int j = 0; j < 4; ++j) p[j] = 0.f;
#pragma unroll
        for (int ng = 0; ng < 8; ++ng) {
            float4 q[4];
#pragma unroll
            for (int m = 0; m < 4; ++m) q[m] = cw4[ng * 4 + m];
#pragma unroll
            for (int m = 0; m < 4; ++m) {
                int n = ng * 4 + m;
                float ar_ = zr[n], ai_ = zi[n];
#pragma unroll
                for (int j = 0; j < 4; ++j) {
                    float nr = fmaf(q[m].x, ar_, fmaf(-q[m].y, ai_, u[j]));
                    ai_ = fmaf(q[m].x, ai_, q[m].y * ar_);
                    ar_ = nr;
                    p[j] = fmaf(q[m].z, ar_, fmaf(-q[m].w, ai_, p[j]));
                }
                zr[n] = ar_; zi[n] = ai_;
            }
        }
#pragma unroll
        for (int j = 0; j < 4; ++j) {
            float y = fmaf(Dh, u[j], 2.f * p[j]);
            int t = t4 * 4 + j;
            gb[(size_t)t * 16384] = f2bf(gelu_tanh(y));
        }
        xa = na; xbv = nb;
    }
}

// ---------------------------------------------------------------------------
// k_mix: bf16 MFMA GLU mix + pooled decode. One block per (b,T): 64 l'-cols.
// C[m=g(256)][n=v(64)] = (Whi+Wlo)[g][h] x gy[h][v], K=128, fp32 acc.
// Waves 0,1: a-part (g<128); waves 2,3: gate (g>=128) -> sigmoid via LDS.
// ---------------------------------------------------------------------------
#define BPAD 136   // Bt row stride in ushorts (16B-aligned, odd dword count)
#define GPAD 66    // gate row stride in floats
__global__ __launch_bounds__(256) void k_mix(
    const unsigned short* __restrict__ Whi, const unsigned short* __restrict__ Wlo,
    const unsigned short* __restrict__ gyb, const float* __restrict__ out_b,
    const float* __restrict__ dec_w, float* __restrict__ out)
{
    __shared__ unsigned short Bt[64 * BPAD];   // [v][h] transposed gy tile
    __shared__ float gateL[128 * GPAD];        // sigmoid(z_gate)

    const int blk = blockIdx.x;                // = b*128 + T
    const int b = blk >> 7;
    const int tid = threadIdx.x;
    const int wq = tid >> 6, lane = tid & 63;

    // ---- stage gy slice (128h x 64v bf16, contiguous 16 KB) transposed ----
    const unsigned short* gys = gyb + (size_t)blk * 8192;
#pragma unroll
    for (int it = 0; it < 4; ++it) {
        int idx = it * 256 + tid;              // 0..1023
        int h = idx >> 3, v0 = (idx & 7) * 8;
        uint4 q = *(const uint4*)(gys + h * 64 + v0);
        Bt[(v0 + 0) * BPAD + h] = (unsigned short)(q.x & 0xFFFF);
        Bt[(v0 + 1) * BPAD + h] = (unsigned short)(q.x >> 16);
        Bt[(v0 + 2) * BPAD + h] = (unsigned short)(q.y & 0xFFFF);
        Bt[(v0 + 3) * BPAD + h] = (unsigned short)(q.y >> 16);
        Bt[(v0 + 4) * BPAD + h] = (unsigned short)(q.z & 0xFFFF);
        Bt[(v0 + 5) * BPAD + h] = (unsigned short)(q.z >> 16);
        Bt[(v0 + 6) * BPAD + h] = (unsigned short)(q.w & 0xFFFF);
        Bt[(v0 + 7) * BPAD + h] = (unsigned short)(q.w >> 16);
    }
    __syncthreads();

    // ---- MFMA K-loop: wave wq owns g-strip [64*wq, 64*wq+64) ----
    const int gbase = wq * 64;
    const int mrow = lane & 15;                // m/n-tile row/col
    const int quad = lane >> 4;                // k-group
    f32x4 acc[4][4];
#pragma unroll
    for (int mt = 0; mt < 4; ++mt)
#pragma unroll
        for (int nt = 0; nt < 4; ++nt)
            acc[mt][nt] = (f32x4){0.f, 0.f, 0.f, 0.f};

#pragma unroll
    for (int k = 0; k < 4; ++k) {
        const int h0 = k * 32 + quad * 8;
        short8 bfr[4];
#pragma unroll
        for (int nt = 0; nt < 4; ++nt) {
            int v = nt * 16 + mrow;
            bfr[nt] = *(const short8*)(Bt + v * BPAD + h0);
        }
#pragma unroll
        for (int mt = 0; mt < 4; ++mt) {
            int g = gbase + mt * 16 + mrow;
            short8 ah = *(const short8*)(Whi + g * 128 + h0);
            short8 al = *(const short8*)(Wlo + g * 128 + h0);
#pragma unroll
            for (int nt = 0; nt < 4; ++nt) {
                acc[mt][nt] = __builtin_amdgcn_mfma_f32_16x16x32_bf16(
                    ah, bfr[nt], acc[mt][nt], 0, 0, 0);
                acc[mt][nt] = __builtin_amdgcn_mfma_f32_16x16x32_bf16(
                    al, bfr[nt], acc[mt][nt], 0, 0, 0);
            }
        }
    }

    // ---- epilogue: C row g = gbase + mt*16 + quad*4 + r, col v = nt*16+mrow
    float4 ob[4];
#pragma unroll
    for (int mt = 0; mt < 4; ++mt)
        ob[mt] = *(const float4*)(out_b + gbase + mt * 16 + quad * 4);

    if (wq >= 2) {                             // gate waves: sigmoid -> LDS
#pragma unroll
        for (int mt = 0; mt < 4; ++mt) {
            int gL = (gbase - 128) + mt * 16 + quad * 4;
#pragma unroll
            for (int nt = 0; nt < 4; ++nt) {
                int v = nt * 16 + mrow;
#pragma unroll
                for (int r = 0; r < 4; ++r) {
                    float zg = acc[mt][nt][r] + ob[mt][r];
                    gateL[(gL + r) * GPAD + v] =
                        __fdividef(1.f, 1.f + __expf(-zg));
                }
            }
        }
    }
    __syncthreads();

    if (wq < 2) {                              // a waves: GLU + dec dot + pool
        float4 dv[4];
#pragma unroll
        for (int mt = 0; mt < 4; ++mt)
            dv[mt] = *(const float4*)(dec_w + gbase + mt * 16 + quad * 4);
        float s = 0.f;
#pragma unroll
        for (int mt = 0; mt < 4; ++mt) {
            int gL = gbase + mt * 16 + quad * 4;
#pragma unroll
            for (int nt = 0; nt < 4; ++nt) {
                int v = nt * 16 + mrow;
#pragma unroll
                for (int r = 0; r < 4; ++r) {
                    float a = acc[mt][nt][r] + ob[mt][r];
                    float sg = gateL[(gL + r) * GPAD + v];
                    s = fmaf(dv[mt][r], a * sg, s);
                }
            }
        }
#pragma unroll
        for (int off = 32; off; off >>= 1) s += __shfl_down(s, off, 64);
        if (lane == 0) atomicAdd(out + b, s * (1.0f / (float)L_));
    }
}

// ---------------------------------------------------------------------------
extern "C" void kernel_launch(void* const* d_in, const int* in_sizes, int n_in,
                              void* d_out, int out_size, void* d_ws, size_t ws_size,
                              hipStream_t stream)
{
    const float* x         = (const float*)d_in[0];
    const float* enc_w     = (const float*)d_in[1];
    const float* enc_b     = (const float*)d_in[2];
    const float* log_dt    = (const float*)d_in[3];
    const float* log_A_real= (const float*)d_in[4];
    const float* A_imag    = (const float*)d_in[5];
    const float* C_re      = (const float*)d_in[6];
    const float* C_im      = (const float*)d_in[7];
    const float* Dp        = (const float*)d_in[8];
    const float* out_w     = (const float*)d_in[9];
    const float* out_b     = (const float*)d_in[10];
    const float* dec_w     = (const float*)d_in[11];
    const float* dec_b     = (const float*)d_in[12];
    float* out = (float*)d_out;

    char* ws = (char*)d_ws;
    unsigned short* Whi = (unsigned short*)(ws);
    unsigned short* Wlo = (unsigned short*)(ws + 65536);
    unsigned short* gyb = (unsigned short*)(ws + 131072);

    k_setup<<<129, 256, 0, stream>>>(out_w, dec_b, out, Whi, Wlo);
    k_s4d<<<B_ * H_, C_, 0, stream>>>(x, enc_w, enc_b, log_dt, log_A_real,
                                      A_imag, C_re, C_im, Dp, gyb);
    k_mix<<<B_ * 128, 256, 0, stream>>>(Whi, Wlo, gyb, out_b, dec_w, out);
}

// Round 6
// 192.998 us; speedup vs baseline: 1.3695x; 1.3695x over previous
//
#include <hip/hip_runtime.h>
#include <math.h>

// Problem dims (fixed by the reference)
#define B_ 8
#define L_ 8192
#define H_ 128
#define N_ 32
#define C_ 128   // chunks along L (= threads per k_s4d block)
#define T_ 64    // chunk length (C_*T_ == L_)

// ws layout:
//   Whi ushort[256*128] @ 0        (64 KB)  bf16 hi part of out_w, [g][h]
//   Wlo ushort[256*128] @ 65536    (64 KB)  bf16 lo part (w - hi)
//   gyb ushort[B_*H_*L_] @ 131072  (16 MB)  bf16 gy, layout [b][T(128)][h(128)][v(64)]
// l' = T*64+v = t*128+c (fixed permutation of l; mix+pool is order-invariant)

typedef __attribute__((ext_vector_type(8))) short short8;
typedef __attribute__((ext_vector_type(4))) float f32x4;

__device__ __forceinline__ unsigned short f2bf(float f) {
    unsigned int u = __float_as_uint(f);
    return (unsigned short)((u + 0x7FFFu + ((u >> 16) & 1u)) >> 16);
}
__device__ __forceinline__ float bf2f(unsigned short h) {
    return __uint_as_float(((unsigned int)h) << 16);
}

__device__ __forceinline__ float gelu_tanh(float y) {
    float t = 0.7978845608028654f * fmaf(0.044715f, y * y * y, y);
    float e = __expf(2.f * t);
    float th = 1.f - __fdividef(2.f, e + 1.f);
    return 0.5f * y * (1.f + th);
}

// ---------------------------------------------------------------------------
// k_setup: split out_w into bf16 hi/lo ([g][h] = MFMA A layout) + out init
// ---------------------------------------------------------------------------
__global__ __launch_bounds__(256) void k_setup(
    const float* __restrict__ out_w, const float* __restrict__ dec_b,
    float* __restrict__ out, unsigned short* __restrict__ Whi,
    unsigned short* __restrict__ Wlo)
{
    int blk = blockIdx.x, tid = threadIdx.x;
    if (blk < 128) {
        int idx = blk * 256 + tid;            // 0..32767 = g*128+h
        float w = out_w[idx];
        unsigned short hi = f2bf(w);
        Whi[idx] = hi;
        Wlo[idx] = f2bf(w - bf2f(hi));
    } else {
        if (tid < B_) out[tid] = dec_b[0];
    }
}

// ---------------------------------------------------------------------------
// k_s4d: fused encoder + chunked S4D scan + skip + GELU -> bf16 gy.
// Block=(b,h), 128 threads (2 waves), thread = chunk c.
// PLAIN __launch_bounds__(128): any min-wave bound shrinks VGPR below the
// ~170-reg working set and spills (R3: 3.7GB / 7x; R5: 316MB / 1.5x).
// ---------------------------------------------------------------------------
__global__ __launch_bounds__(128) void k_s4d(
    const float* __restrict__ x, const float* __restrict__ enc_w,
    const float* __restrict__ enc_b, const float* __restrict__ log_dt,
    const float* __restrict__ log_A_real, const float* __restrict__ A_imag,
    const float* __restrict__ C_re, const float* __restrict__ C_im,
    const float* __restrict__ Dp, unsigned short* __restrict__ gyb)
{
    const int bh = blockIdx.x;
    const int b = bh >> 7, h = bh & (H_ - 1);
    const int c = threadIdx.x;
    const int lane = c & 63, wv = c >> 6;

    __shared__ float4 cw4[N_];        // (wr, wi, coef_r, coef_i)
    __shared__ float4 pw[N_];         // (w2r, w2i, wr, wi)
    __shared__ float2 wTpow[7][N_];   // wT^(2^k)
    __shared__ float2 Sx[N_][64];     // wave-0 inclusive scans (16 KB)

    if (c < N_) {
        int idx = h * N_ + c;
        float dt = expf(log_dt[h]);
        float Ar = -expf(log_A_real[idx]);
        float Ai = A_imag[idx];
        float ar = dt * Ar, ai = dt * Ai;
        float er = expf(ar);
        float wr = er * cosf(ai), wi = er * sinf(ai);
        float numr = wr - 1.f, numi = wi;
        float inv = 1.f / (Ar * Ar + Ai * Ai);
        float qr = (numr * Ar + numi * Ai) * inv;
        float qi = (numi * Ar - numr * Ai) * inv;
        cw4[c] = make_float4(wr, wi, C_re[idx] * qr - C_im[idx] * qi,
                                     C_re[idx] * qi + C_im[idx] * qr);
        pw[c] = make_float4(wr * wr - wi * wi, 2.f * wr * wi, wr, wi);
        float erT = expf(ar * (float)T_);
        float pr = erT * cosf(ai * (float)T_), pi = erT * sinf(ai * (float)T_);
#pragma unroll
        for (int k = 0; k < 7; ++k) {
            wTpow[k][c] = make_float2(pr, pi);
            float nr = pr * pr - pi * pi;
            pi = 2.f * pr * pi; pr = nr;
        }
    }
    __syncthreads();

    const float2* xb = (const float2*)x + (size_t)b * L_ + c * T_;
    const float ew0 = enc_w[h], ew1 = enc_w[H_ + h], eb = enc_b[h];

    // ---- Phase 1: E[c] via w^2 double-steps; 8-timestep u tile, n by 4 ----
    float zr[N_], zi[N_];
#pragma unroll
    for (int n = 0; n < N_; ++n) { zr[n] = 0.f; zi[n] = 0.f; }

#pragma unroll 1
    for (int tt = 0; tt < T_ / 8; ++tt) {       // 8 tiles of 8 timesteps
        float u[8];
        const float4* xq = (const float4*)xb + tt * 4;
#pragma unroll
        for (int j = 0; j < 4; ++j) {
            float4 xv = xq[j];
            u[2 * j]     = fmaf(xv.x, ew0, fmaf(xv.y, ew1, eb));
            u[2 * j + 1] = fmaf(xv.z, ew0, fmaf(xv.w, ew1, eb));
        }
#pragma unroll
        for (int ng = 0; ng < 8; ++ng) {
            float4 q[4];
#pragma unroll
            for (int m = 0; m < 4; ++m) q[m] = pw[ng * 4 + m];
#pragma unroll
            for (int m = 0; m < 4; ++m) {
                int n = ng * 4 + m;
                float ar_ = zr[n], ai_ = zi[n];
#pragma unroll
                for (int t2 = 0; t2 < 4; ++t2) {
                    float ua = u[2 * t2], ub = u[2 * t2 + 1];
                    float mr = fmaf(q[m].z, ua, ub);
                    float mi = q[m].w * ua;
                    float nr = fmaf(q[m].x, ar_, fmaf(-q[m].y, ai_, mr));
                    ai_ = fmaf(q[m].x, ai_, fmaf(q[m].y, ar_, mi));
                    ar_ = nr;
                }
                zr[n] = ar_; zi[n] = ai_;
            }
        }
    }

    // ---- Phase 2: scan over chunks ----
#pragma unroll
    for (int k = 0; k < 6; ++k) {
        int s = 1 << k;
        float mask = (lane >= s) ? 1.f : 0.f;
#pragma unroll
        for (int n = 0; n < N_; ++n) {
            float2 q = wTpow[k][n];
            float vr = __shfl_up(zr[n], s, 64);
            float vi = __shfl_up(zi[n], s, 64);
            float adr = fmaf(q.x, vr, -(q.y * vi));
            float adi = fmaf(q.x, vi, q.y * vr);
            zr[n] = fmaf(mask, adr, zr[n]);
            zi[n] = fmaf(mask, adi, zi[n]);
        }
    }
    if (wv == 0) {
#pragma unroll
        for (int n = 0; n < N_; ++n) Sx[n][lane] = make_float2(zr[n], zi[n]);
    }
    __syncthreads();
    if (wv == 1) {
#pragma unroll
        for (int n = 0; n < N_; ++n) {
            float2 q = wTpow[6][n];
            float2 v = Sx[n][lane];
            zr[n] = fmaf(q.x, v.x, fmaf(-q.y, v.y, zr[n]));
            zi[n] = fmaf(q.x, v.y, fmaf(q.y, v.x, zi[n]));
        }
    }
    {
        bool l0 = (lane == 0);
#pragma unroll
        for (int n = 0; n < N_; ++n) {
            float2 bv = Sx[n][63];
            float br = (wv == 1) ? bv.x : 0.f;
            float bi = (wv == 1) ? bv.y : 0.f;
            float tr = __shfl_up(zr[n], 1, 64);
            float ti = __shfl_up(zi[n], 1, 64);
            zr[n] = l0 ? br : tr;
            zi[n] = l0 ? bi : ti;
        }
    }

    // ---- Phase 3: replay with incoming state; skip+GELU; bf16 store ----
    // store layout: gyb[((b*128 + (t*2+wv))*128 + h)*64 + lane], t=t4*4+j
    const float Dh = Dp[h];
    unsigned short* gb = gyb + (size_t)b * (128 * 128 * 64)
                             + (size_t)wv * 8192 + h * 64 + lane;
    const float4* xq = (const float4*)xb;
    float4 xa = xq[0], xbv = xq[1];
#pragma unroll 1
    for (int t4 = 0; t4 < T_ / 4; ++t4) {
        float4 na, nb;
        if (t4 < T_ / 4 - 1) { na = xq[2 * t4 + 2]; nb = xq[2 * t4 + 3]; }
        float u[4], p[4];
        u[0] = fmaf(xa.x, ew0, fmaf(xa.y, ew1, eb));
        u[1] = fmaf(xa.z, ew0, fmaf(xa.w, ew1, eb));
        u[2] = fmaf(xbv.x, ew0, fmaf(xbv.y, ew1, eb));
        u[3] = fmaf(xbv.z, ew0, fmaf(xbv.w, ew1, eb));
#pragma unroll
        for (int j = 0; j < 4; ++j) p[j] = 0.f;
#pragma unroll
        for (int ng = 0; ng < 8; ++ng) {
            float4 q[4];
#pragma unroll
            for (int m = 0; m < 4; ++m) q[m] = cw4[ng * 4 + m];
#pragma unroll
            for (int m = 0; m < 4; ++m) {
                int n = ng * 4 + m;
                float ar_ = zr[n], ai_ = zi[n];
#pragma unroll
                for (int j = 0; j < 4; ++j) {
                    float nr = fmaf(q[m].x, ar_, fmaf(-q[m].y, ai_, u[j]));
                    ai_ = fmaf(q[m].x, ai_, q[m].y * ar_);
                    ar_ = nr;
                    p[j] = fmaf(q[m].z, ar_, fmaf(-q[m].w, ai_, p[j]));
                }
                zr[n] = ar_; zi[n] = ai_;
            }
        }
#pragma unroll
        for (int j = 0; j < 4; ++j) {
            float y = fmaf(Dh, u[j], 2.f * p[j]);
            int t = t4 * 4 + j;
            gb[(size_t)t * 16384] = f2bf(gelu_tanh(y));
        }
        xa = na; xbv = nb;
    }
}

// ---------------------------------------------------------------------------
// k_mix: bf16 MFMA GLU mix + pooled decode. One block per (b,T): 64 l'-cols.
// Unchanged structure vs R5 (need its counters); only the atomic ending is
// consolidated to ONE device atomic per block.
// ---------------------------------------------------------------------------
#define BPAD 136   // Bt row stride in ushorts (16B-aligned)
#define GPAD 66    // gate row stride in floats
__global__ __launch_bounds__(256) void k_mix(
    const unsigned short* __restrict__ Whi, const unsigned short* __restrict__ Wlo,
    const unsigned short* __restrict__ gyb, const float* __restrict__ out_b,
    const float* __restrict__ dec_w, float* __restrict__ out)
{
    __shared__ unsigned short Bt[64 * BPAD];   // [v][h] transposed gy tile
    __shared__ float gateL[128 * GPAD];        // sigmoid(z_gate)
    __shared__ float red[2];

    const int blk = blockIdx.x;                // = b*128 + T
    const int b = blk >> 7;
    const int tid = threadIdx.x;
    const int wq = tid >> 6, lane = tid & 63;

    // ---- stage gy slice (128h x 64v bf16, contiguous 16 KB) transposed ----
    const unsigned short* gys = gyb + (size_t)blk * 8192;
#pragma unroll
    for (int it = 0; it < 4; ++it) {
        int idx = it * 256 + tid;              // 0..1023
        int h = idx >> 3, v0 = (idx & 7) * 8;
        uint4 q = *(const uint4*)(gys + h * 64 + v0);
        Bt[(v0 + 0) * BPAD + h] = (unsigned short)(q.x & 0xFFFF);
        Bt[(v0 + 1) * BPAD + h] = (unsigned short)(q.x >> 16);
        Bt[(v0 + 2) * BPAD + h] = (unsigned short)(q.y & 0xFFFF);
        Bt[(v0 + 3) * BPAD + h] = (unsigned short)(q.y >> 16);
        Bt[(v0 + 4) * BPAD + h] = (unsigned short)(q.z & 0xFFFF);
        Bt[(v0 + 5) * BPAD + h] = (unsigned short)(q.z >> 16);
        Bt[(v0 + 6) * BPAD + h] = (unsigned short)(q.w & 0xFFFF);
        Bt[(v0 + 7) * BPAD + h] = (unsigned short)(q.w >> 16);
    }
    __syncthreads();

    // ---- MFMA K-loop: wave wq owns g-strip [64*wq, 64*wq+64) ----
    const int gbase = wq * 64;
    const int mrow = lane & 15;
    const int quad = lane >> 4;
    f32x4 acc[4][4];
#pragma unroll
    for (int mt = 0; mt < 4; ++mt)
#pragma unroll
        for (int nt = 0; nt < 4; ++nt)
            acc[mt][nt] = (f32x4){0.f, 0.f, 0.f, 0.f};

#pragma unroll
    for (int k = 0; k < 4; ++k) {
        const int h0 = k * 32 + quad * 8;
        short8 bfr[4];
#pragma unroll
        for (int nt = 0; nt < 4; ++nt) {
            int v = nt * 16 + mrow;
            bfr[nt] = *(const short8*)(Bt + v * BPAD + h0);
        }
#pragma unroll
        for (int mt = 0; mt < 4; ++mt) {
            int g = gbase + mt * 16 + mrow;
            short8 ah = *(const short8*)(Whi + g * 128 + h0);
            short8 al = *(const short8*)(Wlo + g * 128 + h0);
#pragma unroll
            for (int nt = 0; nt < 4; ++nt) {
                acc[mt][nt] = __builtin_amdgcn_mfma_f32_16x16x32_bf16(
                    ah, bfr[nt], acc[mt][nt], 0, 0, 0);
                acc[mt][nt] = __builtin_amdgcn_mfma_f32_16x16x32_bf16(
                    al, bfr[nt], acc[mt][nt], 0, 0, 0);
            }
        }
    }

    // ---- epilogue: C row g = gbase + mt*16 + quad*4 + r, col v = nt*16+mrow
    float4 ob[4];
#pragma unroll
    for (int mt = 0; mt < 4; ++mt)
        ob[mt] = *(const float4*)(out_b + gbase + mt * 16 + quad * 4);

    if (wq >= 2) {                             // gate waves: sigmoid -> LDS
#pragma unroll
        for (int mt = 0; mt < 4; ++mt) {
            int gL = (gbase - 128) + mt * 16 + quad * 4;
#pragma unroll
            for (int nt = 0; nt < 4; ++nt) {
                int v = nt * 16 + mrow;
#pragma unroll
                for (int r = 0; r < 4; ++r) {
                    float zg = acc[mt][nt][r] + ob[mt][r];
                    gateL[(gL + r) * GPAD + v] =
                        __fdividef(1.f, 1.f + __expf(-zg));
                }
            }
        }
    }
    __syncthreads();

    if (wq < 2) {                              // a waves: GLU + dec dot + pool
        float4 dv[4];
#pragma unroll
        for (int mt = 0; mt < 4; ++mt)
            dv[mt] = *(const float4*)(dec_w + gbase + mt * 16 + quad * 4);
        float s = 0.f;
#pragma unroll
        for (int mt = 0; mt < 4; ++mt) {
            int gL = gbase + mt * 16 + quad * 4;
#pragma unroll
            for (int nt = 0; nt < 4; ++nt) {
                int v = nt * 16 + mrow;
#pragma unroll
                for (int r = 0; r < 4; ++r) {
                    float a = acc[mt][nt][r] + ob[mt][r];
                    float sg = gateL[(gL + r) * GPAD + v];
                    s = fmaf(dv[mt][r], a * sg, s);
                }
            }
        }
#pragma unroll
        for (int off = 32; off; off >>= 1) s += __shfl_down(s, off, 64);
        if (lane == 0) red[wq] = s;
    }
    __syncthreads();
    if (tid == 0)                              // ONE atomic per block
        atomicAdd(out + b, (red[0] + red[1]) * (1.0f / (float)L_));
}

// ---------------------------------------------------------------------------
extern "C" void kernel_launch(void* const* d_in, const int* in_sizes, int n_in,
                              void* d_out, int out_size, void* d_ws, size_t ws_size,
                              hipStream_t stream)
{
    const float* x         = (const float*)d_in[0];
    const float* enc_w     = (const float*)d_in[1];
    const float* enc_b     = (const float*)d_in[2];
    const float* log_dt    = (const float*)d_in[3];
    const float* log_A_real= (const float*)d_in[4];
    const float* A_imag    = (const float*)d_in[5];
    const float* C_re      = (const float*)d_in[6];
    const float* C_im      = (const float*)d_in[7];
    const float* Dp        = (const float*)d_in[8];
    const float* out_w     = (const float*)d_in[9];
    const float* out_b     = (const float*)d_in[10];
    const float* dec_w     = (const float*)d_in[11];
    const float* dec_b     = (const float*)d_in[12];
    float* out = (float*)d_out;

    char* ws = (char*)d_ws;
    unsigned short* Whi = (unsigned short*)(ws);
    unsigned short* Wlo = (unsigned short*)(ws + 65536);
    unsigned short* gyb = (unsigned short*)(ws + 131072);

    k_setup<<<129, 256, 0, stream>>>(out_w, dec_b, out, Whi, Wlo);
    k_s4d<<<B_ * H_, C_, 0, stream>>>(x, enc_w, enc_b, log_dt, log_A_real,
                                      A_imag, C_re, C_im, Dp, gyb);
    k_mix<<<B_ * 128, 256, 0, stream>>>(Whi, Wlo, gyb, out_b, dec_w, out);
}